// Round 9
// baseline (652.335 us; speedup 1.0000x reference)
//
#include <hip/hip_runtime.h>
#include <math.h>

#define HDIM 2048
#define OUTN 32000
#define KOUT 3072
#define NPART 2000   // logits blocks == (m,s) partial pairs

__device__ __forceinline__ float wave_reduce_sum(float v) {
    #pragma unroll
    for (int off = 32; off > 0; off >>= 1)
        v += __shfl_down(v, off, 64);
    return v;
}

__device__ __forceinline__ float dot4(float4 a, float4 b) {
    return a.x * b.x + a.y * b.y + a.z * b.z + a.w * b.w;
}

// Non-temporal float4 load: weights are streamed exactly once per invocation;
// 'nt' keeps the 661 MB stream from evicting the reused broadcast vectors.
typedef float nfloat4 __attribute__((ext_vector_type(4)));
__device__ __forceinline__ float4 ldnt4(const float4* p) {
    nfloat4 v = __builtin_nontemporal_load((const nfloat4*)p);
    return make_float4(v.x, v.y, v.z, v.w);
}

__device__ __forceinline__ float sigmoidf_(float x) {
    return 1.0f / (1.0f + __expf(-x));
}

// LSTM gate GEMV, batch=1. Grid: 512 blocks x 256 threads (2048 waves).
// Wave g = blockIdx*4+wave owns 4 CONTIGUOUS gate rows r0=4g..4g+3 of the
// [8192,2048] matrices — one contiguous 32 KB span per matrix per wave
// (vs the old layout's four streams 16 MB apart, which thrashed DRAM pages).
// Phase 1 streams w_ih rows against x; phase 2 streams w_hh rows against h.
// Writes pre-activations: gates[r] = wi[r]·x + wh[r]·h + b_ih[r] + b_hh[r].
__global__ __launch_bounds__(256) void lstm_gemv(
    const float* __restrict__ xa,    // x[0:1024]
    const float* __restrict__ xb,    // x[1024:2048]
    const float* __restrict__ h,     // [2048]
    const float* __restrict__ w_ih,  // [8192, 2048] row-major
    const float* __restrict__ w_hh,  // [8192, 2048]
    const float* __restrict__ b_ih,  // [8192]
    const float* __restrict__ b_hh,  // [8192]
    float* __restrict__ gates)       // [8192] pre-activations
{
    const int wave = threadIdx.x >> 6;
    const int lane = threadIdx.x & 63;
    const int g    = blockIdx.x * 4 + wave;  // 0..2047
    const int r0   = g * 4;                  // 4 contiguous rows

    const float4* wi  = (const float4*)(w_ih + (size_t)r0 * HDIM); // 4x512 f4
    const float4* wh  = (const float4*)(w_hh + (size_t)r0 * HDIM);
    const float4* xa4 = (const float4*)xa;   // 256 float4
    const float4* xb4 = (const float4*)xb;   // 256 float4
    const float4* h4  = (const float4*)h;    // 512 float4

    float a0 = 0.f, a1 = 0.f, a2 = 0.f, a3 = 0.f;
    #pragma unroll
    for (int it = 0; it < 8; ++it) {
        const int k4 = it * 64 + lane;                  // float4 index in row
        float4 xv = (it < 4) ? xa4[k4] : xb4[k4 - 256]; // compile-time select
        a0 += dot4(ldnt4(&wi[k4]),        xv);          // row stride 512 f4
        a1 += dot4(ldnt4(&wi[k4 + 512]),  xv);
        a2 += dot4(ldnt4(&wi[k4 + 1024]), xv);
        a3 += dot4(ldnt4(&wi[k4 + 1536]), xv);
    }
    #pragma unroll
    for (int it = 0; it < 8; ++it) {
        const int k4 = it * 64 + lane;
        float4 hv = h4[k4];
        a0 += dot4(ldnt4(&wh[k4]),        hv);
        a1 += dot4(ldnt4(&wh[k4 + 512]),  hv);
        a2 += dot4(ldnt4(&wh[k4 + 1024]), hv);
        a3 += dot4(ldnt4(&wh[k4 + 1536]), hv);
    }
    a0 = wave_reduce_sum(a0);
    a1 = wave_reduce_sum(a1);
    a2 = wave_reduce_sum(a2);
    a3 = wave_reduce_sum(a3);

    if (lane == 0) {
        float4 bi = ((const float4*)b_ih)[g];  // rows r0..r0+3 == f4 index g
        float4 bh = ((const float4*)b_hh)[g];
        ((float4*)gates)[g] = make_float4(a0 + bi.x + bh.x,
                                          a1 + bi.y + bh.y,
                                          a2 + bi.z + bh.z,
                                          a3 + bi.w + bh.w);
    }
}

// Pointwise LSTM cell update from pre-activations. Grid: 8 x 256 == 2048.
// gates layout is gate-major (PyTorch row order): i | f | g | o.
__global__ __launch_bounds__(256) void lstm_point(
    const float* __restrict__ gates,  // [8192]
    const float* __restrict__ c,      // [2048]
    float* __restrict__ h_out,        // [2048]
    float* __restrict__ c_out)        // [2048]
{
    const int n = blockIdx.x * 256 + threadIdx.x;
    float gi = sigmoidf_(gates[n]);
    float gf = sigmoidf_(gates[HDIM + n]);
    float gg = tanhf(gates[2 * HDIM + n]);
    float go = sigmoidf_(gates[3 * HDIM + n]);
    float cn = gf * c[n] + gi * gg;
    float hn = go * tanhf(cn);
    c_out[n] = cn;
    h_out[n] = hn;
}

// logits[row] = dot(w_out[row,:], concat(category, h2)) + b_out[row]
// Grid: 2000 blocks x 256 threads. Block b: rows b*16 + wave*4 + {0..3}.
// Each wave streams 4 contiguous 12 KB rows + broadcast vector; also emits
// the block's online-softmax partial (max, sumexp) for the LSE pass.
__global__ __launch_bounds__(256) void logits_kernel(
    const float* __restrict__ cat,     // [1024]
    const float* __restrict__ h2,      // [2048]
    const float* __restrict__ w_out,   // [32000, 3072]
    const float* __restrict__ b_out,   // [32000]
    float* __restrict__ logits,        // [32000]
    float2* __restrict__ partial)      // [2000] (m, s) per block
{
    const int wave = threadIdx.x >> 6;
    const int lane = threadIdx.x & 63;
    const int row0 = blockIdx.x * 16 + wave * 4;

    const float4* w4 = (const float4*)(w_out + (size_t)row0 * KOUT);
    const float4* c4 = (const float4*)cat;  // 256 float4
    const float4* h4 = (const float4*)h2;   // 512 float4

    float a0 = 0.f, a1 = 0.f, a2 = 0.f, a3 = 0.f;
    #pragma unroll
    for (int it = 0; it < 12; ++it) {
        const int k4 = it * 64 + lane;
        float4 v = (it < 4) ? c4[k4] : h4[k4 - 256];
        a0 += dot4(ldnt4(&w4[k4]),        v);   // row stride = KOUT/4 = 768 f4
        a1 += dot4(ldnt4(&w4[k4 + 768]),  v);
        a2 += dot4(ldnt4(&w4[k4 + 1536]), v);
        a3 += dot4(ldnt4(&w4[k4 + 2304]), v);
    }
    a0 = wave_reduce_sum(a0);
    a1 = wave_reduce_sum(a1);
    a2 = wave_reduce_sum(a2);
    a3 = wave_reduce_sum(a3);

    __shared__ float sm[4], ss[4];
    if (lane == 0) {
        a0 += b_out[row0];
        a1 += b_out[row0 + 1];
        a2 += b_out[row0 + 2];
        a3 += b_out[row0 + 3];
        *(float4*)(logits + row0) = make_float4(a0, a1, a2, a3); // row0 % 4 == 0
        float m = fmaxf(fmaxf(a0, a1), fmaxf(a2, a3));
        float s = __expf(a0 - m) + __expf(a1 - m) + __expf(a2 - m) + __expf(a3 - m);
        sm[wave] = m; ss[wave] = s;
    }
    __syncthreads();
    if (threadIdx.x == 0) {
        float M = sm[0], S = ss[0];
        #pragma unroll
        for (int w = 1; w < 4; ++w) {
            float mn = fmaxf(M, sm[w]);
            S = S * __expf(M - mn) + ss[w] * __expf(sm[w] - mn);
            M = mn;
        }
        partial[blockIdx.x] = make_float2(M, S);
    }
}

// Combine 2000 (m, s) partials -> *logz = M + log(S). Single block.
// Every thread gets >=1 pair (2000 >= 1024) so all lane maxes are finite
// before the shuffle merge (avoids -inf - -inf = NaN).
__global__ __launch_bounds__(1024) void lse_combine(
    const float2* __restrict__ partial, float* __restrict__ logz)
{
    float m = -INFINITY, s = 0.f;
    for (int i = threadIdx.x; i < NPART; i += 1024) {
        float2 p  = partial[i];
        float  mn = fmaxf(m, p.x);
        s = s * __expf(m - mn) + p.y * __expf(p.x - mn); // first iter: 0*exp(-inf)=0
        m = mn;
    }
    #pragma unroll
    for (int off = 32; off > 0; off >>= 1) {
        float m2 = __shfl_down(m, off, 64);
        float s2 = __shfl_down(s, off, 64);
        float mn = fmaxf(m, m2);
        s = s * __expf(m - mn) + s2 * __expf(m2 - mn);
        m = mn;
    }
    __shared__ float smm[16], sss[16];
    const int wave = threadIdx.x >> 6;
    const int lane = threadIdx.x & 63;
    if (lane == 0) { smm[wave] = m; sss[wave] = s; }
    __syncthreads();
    if (threadIdx.x == 0) {
        float M = smm[0], S = sss[0];
        for (int w = 1; w < 16; ++w) {
            float mn = fmaxf(M, smm[w]);
            S = S * __expf(M - mn) + sss[w] * __expf(smm[w] - mn);
            M = mn;
        }
        *logz = M + logf(S);
    }
}

// logp[i] = logits[i] - logZ.  Grid: 125 x 256 == 32000 exactly.
__global__ __launch_bounds__(256) void sub_kernel(
    const float* __restrict__ logits, const float* __restrict__ logz,
    float* __restrict__ out)
{
    const int i = blockIdx.x * 256 + threadIdx.x;
    out[i] = logits[i] - *logz;
}

extern "C" void kernel_launch(void* const* d_in, const int* in_sizes, int n_in,
                              void* d_out, int out_size, void* d_ws, size_t ws_size,
                              hipStream_t stream) {
    const float* category = (const float*)d_in[0];   // [1024]
    const float* input    = (const float*)d_in[1];   // [1024]
    const float* hidden   = (const float*)d_in[2];   // [2,1,2048]
    const float* cell     = (const float*)d_in[3];   // [2,1,2048]
    const float* w_ih_l0  = (const float*)d_in[4];
    const float* w_hh_l0  = (const float*)d_in[5];
    const float* b_ih_l0  = (const float*)d_in[6];
    const float* b_hh_l0  = (const float*)d_in[7];
    const float* w_ih_l1  = (const float*)d_in[8];
    const float* w_hh_l1  = (const float*)d_in[9];
    const float* b_ih_l1  = (const float*)d_in[10];
    const float* b_hh_l1  = (const float*)d_in[11];
    const float* w_out    = (const float*)d_in[12];
    const float* b_out    = (const float*)d_in[13];

    float* out  = (float*)d_out;
    float* logp = out;                    // [32000]
    float* h1   = out + OUTN;             // new_hidden[0]
    float* h2   = out + OUTN + HDIM;      // new_hidden[1]
    float* c1   = out + OUTN + 2 * HDIM;  // new_cell[0]
    float* c2   = out + OUTN + 3 * HDIM;  // new_cell[1]

    // Workspace layout (16 B aligned slots): gates first so its float4
    // stores are aligned, then logits (offset 32 KB, 16-aligned), then logz.
    float* gates  = (float*)d_ws;         // [8192] (reused by both layers)
    float* logits = gates + 4 * HDIM;     // [32000]
    float* logz   = logits + OUTN;        // [1]
    // Stage (m,s) partials in the logp output region: 16 KB of the 128 KB
    // logp buffer; written by logits_kernel, read by lse_combine, then fully
    // overwritten by sub_kernel (stream order makes this race-free).
    float2* partial = (float2*)logp;

    // layer 0: x = concat(category, input)
    lstm_gemv<<<512, 256, 0, stream>>>(category, input, hidden,
                                       w_ih_l0, w_hh_l0, b_ih_l0, b_hh_l0,
                                       gates);
    lstm_point<<<8, 256, 0, stream>>>(gates, cell, h1, c1);
    // layer 1: x = h1 (contiguous; split into two halves for the shared kernel)
    lstm_gemv<<<512, 256, 0, stream>>>(h1, h1 + 1024, hidden + HDIM,
                                       w_ih_l1, w_hh_l1, b_ih_l1, b_hh_l1,
                                       gates);
    lstm_point<<<8, 256, 0, stream>>>(gates, cell + HDIM, h2, c2);

    logits_kernel<<<NPART, 256, 0, stream>>>(category, h2, w_out, b_out,
                                             logits, partial);
    lse_combine<<<1, 1024, 0, stream>>>(partial, logz);
    sub_kernel<<<OUTN / 256, 256, 0, stream>>>(logits, logz, logp);
}

// Round 10
// 652.062 us; speedup vs baseline: 1.0004x; 1.0004x over previous
//
#include <hip/hip_runtime.h>
#include <math.h>

#define HDIM 2048
#define OUTN 32000
#define KOUT 3072
#define NPART 1000   // logits blocks == (m,s) partial pairs

__device__ __forceinline__ float wave_reduce_sum(float v) {
    #pragma unroll
    for (int off = 32; off > 0; off >>= 1)
        v += __shfl_down(v, off, 64);
    return v;
}

__device__ __forceinline__ float dot4(float4 a, float4 b) {
    return a.x * b.x + a.y * b.y + a.z * b.z + a.w * b.w;
}

// Non-temporal float4 load: weights are streamed exactly once per invocation;
// 'nt' keeps the 661 MB stream from evicting the reused broadcast vectors.
typedef float nfloat4 __attribute__((ext_vector_type(4)));
__device__ __forceinline__ float4 ldnt4(const float4* p) {
    nfloat4 v = __builtin_nontemporal_load((const nfloat4*)p);
    return make_float4(v.x, v.y, v.z, v.w);
}

__device__ __forceinline__ float sigmoidf_(float x) {
    return 1.0f / (1.0f + __expf(-x));
}

// LSTM gate GEMV, batch=1. Grid: 512 blocks x 256 threads (2048 waves).
// Wave g owns 4 contiguous gate rows r0=4g..4g+3 (one 32 KB span per matrix).
// Writes pre-activations: gates[r] = wi[r]·x + wh[r]·h + b_ih[r] + b_hh[r].
__global__ __launch_bounds__(256) void lstm_gemv(
    const float* __restrict__ xa,    // x[0:1024]
    const float* __restrict__ xb,    // x[1024:2048]
    const float* __restrict__ h,     // [2048]
    const float* __restrict__ w_ih,  // [8192, 2048] row-major
    const float* __restrict__ w_hh,  // [8192, 2048]
    const float* __restrict__ b_ih,  // [8192]
    const float* __restrict__ b_hh,  // [8192]
    float* __restrict__ gates)       // [8192] pre-activations
{
    const int wave = threadIdx.x >> 6;
    const int lane = threadIdx.x & 63;
    const int g    = blockIdx.x * 4 + wave;  // 0..2047
    const int r0   = g * 4;                  // 4 contiguous rows

    const float4* wi  = (const float4*)(w_ih + (size_t)r0 * HDIM); // 4x512 f4
    const float4* wh  = (const float4*)(w_hh + (size_t)r0 * HDIM);
    const float4* xa4 = (const float4*)xa;   // 256 float4
    const float4* xb4 = (const float4*)xb;   // 256 float4
    const float4* h4  = (const float4*)h;    // 512 float4

    float a0 = 0.f, a1 = 0.f, a2 = 0.f, a3 = 0.f;
    #pragma unroll
    for (int it = 0; it < 8; ++it) {
        const int k4 = it * 64 + lane;                  // float4 index in row
        float4 xv = (it < 4) ? xa4[k4] : xb4[k4 - 256]; // compile-time select
        a0 += dot4(ldnt4(&wi[k4]),        xv);          // row stride 512 f4
        a1 += dot4(ldnt4(&wi[k4 + 512]),  xv);
        a2 += dot4(ldnt4(&wi[k4 + 1024]), xv);
        a3 += dot4(ldnt4(&wi[k4 + 1536]), xv);
    }
    #pragma unroll
    for (int it = 0; it < 8; ++it) {
        const int k4 = it * 64 + lane;
        float4 hv = h4[k4];
        a0 += dot4(ldnt4(&wh[k4]),        hv);
        a1 += dot4(ldnt4(&wh[k4 + 512]),  hv);
        a2 += dot4(ldnt4(&wh[k4 + 1024]), hv);
        a3 += dot4(ldnt4(&wh[k4 + 1536]), hv);
    }
    a0 = wave_reduce_sum(a0);
    a1 = wave_reduce_sum(a1);
    a2 = wave_reduce_sum(a2);
    a3 = wave_reduce_sum(a3);

    if (lane == 0) {
        float4 bi = ((const float4*)b_ih)[g];  // rows r0..r0+3 == f4 index g
        float4 bh = ((const float4*)b_hh)[g];
        ((float4*)gates)[g] = make_float4(a0 + bi.x + bh.x,
                                          a1 + bi.y + bh.y,
                                          a2 + bi.z + bh.z,
                                          a3 + bi.w + bh.w);
    }
}

// Pointwise LSTM cell update from pre-activations. Grid: 8 x 256 == 2048.
// gates layout is gate-major (PyTorch row order): i | f | g | o.
__global__ __launch_bounds__(256) void lstm_point(
    const float* __restrict__ gates,  // [8192]
    const float* __restrict__ c,      // [2048]
    float* __restrict__ h_out,        // [2048]
    float* __restrict__ c_out)        // [2048]
{
    const int n = blockIdx.x * 256 + threadIdx.x;
    float gi = sigmoidf_(gates[n]);
    float gf = sigmoidf_(gates[HDIM + n]);
    float gg = tanhf(gates[2 * HDIM + n]);
    float go = sigmoidf_(gates[3 * HDIM + n]);
    float cn = gf * c[n] + gi * gg;
    float hn = go * tanhf(cn);
    c_out[n] = cn;
    h_out[n] = hn;
}

// logits[row] = dot(w_out[row,:], concat(category, h2)) + b_out[row]
// Grid: 1000 blocks x 256 threads. Block b: rows b*32 + wave*8 + {0..7}.
// 8 rows per wave amortizes the broadcast concat-vector load 8x and gives
// each wave 8 independent 12 KB weight streams. Emits the block's
// online-softmax partial (max, sumexp) over its 32 rows.
__global__ __launch_bounds__(256) void logits_kernel(
    const float* __restrict__ cat,     // [1024]
    const float* __restrict__ h2,      // [2048]
    const float* __restrict__ w_out,   // [32000, 3072]
    const float* __restrict__ b_out,   // [32000]
    float* __restrict__ logits,        // [32000]
    float2* __restrict__ partial)      // [1000] (m, s) per block
{
    const int wave = threadIdx.x >> 6;
    const int lane = threadIdx.x & 63;
    const int row0 = blockIdx.x * 32 + wave * 8;   // max 999*32+3*8 = 31992

    const float4* w4 = (const float4*)(w_out + (size_t)row0 * KOUT);
    const float4* c4 = (const float4*)cat;  // 256 float4
    const float4* h4 = (const float4*)h2;   // 512 float4

    float a[8] = {0.f, 0.f, 0.f, 0.f, 0.f, 0.f, 0.f, 0.f};
    #pragma unroll
    for (int it = 0; it < 12; ++it) {
        const int k4 = it * 64 + lane;
        float4 v = (it < 4) ? c4[k4] : h4[k4 - 256];
        #pragma unroll
        for (int r = 0; r < 8; ++r)               // row stride = KOUT/4 = 768
            a[r] += dot4(ldnt4(&w4[k4 + r * 768]), v);
    }
    #pragma unroll
    for (int r = 0; r < 8; ++r)
        a[r] = wave_reduce_sum(a[r]);

    __shared__ float sm[4], ss[4];
    if (lane == 0) {
        #pragma unroll
        for (int r = 0; r < 8; ++r)
            a[r] += b_out[row0 + r];
        *(float4*)(logits + row0)     = make_float4(a[0], a[1], a[2], a[3]);
        *(float4*)(logits + row0 + 4) = make_float4(a[4], a[5], a[6], a[7]);
        float m = a[0];
        #pragma unroll
        for (int r = 1; r < 8; ++r) m = fmaxf(m, a[r]);
        float s = 0.f;
        #pragma unroll
        for (int r = 0; r < 8; ++r) s += __expf(a[r] - m);
        sm[wave] = m; ss[wave] = s;
    }
    __syncthreads();
    if (threadIdx.x == 0) {
        float M = sm[0], S = ss[0];
        #pragma unroll
        for (int w = 1; w < 4; ++w) {
            float mn = fmaxf(M, sm[w]);
            S = S * __expf(M - mn) + ss[w] * __expf(sm[w] - mn);
            M = mn;
        }
        partial[blockIdx.x] = make_float2(M, S);
    }
}

// Fused LSE + subtract. Grid: 125 x 256 == 32000 exactly.
// Every block redundantly reduces the 1000 (m,s) partials (8 KB, L2-hot,
// identical deterministic sequence per block) -> logz, then writes its
// 256 outputs. Removes the single-block lse_combine kernel + one launch.
__global__ __launch_bounds__(256) void sub_fused(
    const float* __restrict__ logits,   // [32000]
    const float2* __restrict__ partial, // [1000]
    float* __restrict__ out)            // [32000]
{
    float m = -INFINITY, s = 0.f;
    for (int i = threadIdx.x; i < NPART; i += 256) {  // every thread >=3 pairs
        float2 p  = partial[i];
        float  mn = fmaxf(m, p.x);
        s = s * __expf(m - mn) + p.y * __expf(p.x - mn); // first: 0*exp(-inf)=0
        m = mn;
    }
    #pragma unroll
    for (int off = 32; off > 0; off >>= 1) {
        float m2 = __shfl_down(m, off, 64);
        float s2 = __shfl_down(s, off, 64);
        float mn = fmaxf(m, m2);
        s = s * __expf(m - mn) + s2 * __expf(m2 - mn);
        m = mn;
    }
    __shared__ float smm[4], sss[4], s_logz;
    const int wave = threadIdx.x >> 6;
    const int lane = threadIdx.x & 63;
    if (lane == 0) { smm[wave] = m; sss[wave] = s; }
    __syncthreads();
    if (threadIdx.x == 0) {
        float M = smm[0], S = sss[0];
        #pragma unroll
        for (int w = 1; w < 4; ++w) {
            float mn = fmaxf(M, smm[w]);
            S = S * __expf(M - mn) + sss[w] * __expf(smm[w] - mn);
            M = mn;
        }
        s_logz = M + logf(S);
    }
    __syncthreads();
    const int i = blockIdx.x * 256 + threadIdx.x;
    out[i] = logits[i] - s_logz;
}

extern "C" void kernel_launch(void* const* d_in, const int* in_sizes, int n_in,
                              void* d_out, int out_size, void* d_ws, size_t ws_size,
                              hipStream_t stream) {
    const float* category = (const float*)d_in[0];   // [1024]
    const float* input    = (const float*)d_in[1];   // [1024]
    const float* hidden   = (const float*)d_in[2];   // [2,1,2048]
    const float* cell     = (const float*)d_in[3];   // [2,1,2048]
    const float* w_ih_l0  = (const float*)d_in[4];
    const float* w_hh_l0  = (const float*)d_in[5];
    const float* b_ih_l0  = (const float*)d_in[6];
    const float* b_hh_l0  = (const float*)d_in[7];
    const float* w_ih_l1  = (const float*)d_in[8];
    const float* w_hh_l1  = (const float*)d_in[9];
    const float* b_ih_l1  = (const float*)d_in[10];
    const float* b_hh_l1  = (const float*)d_in[11];
    const float* w_out    = (const float*)d_in[12];
    const float* b_out    = (const float*)d_in[13];

    float* out  = (float*)d_out;
    float* logp = out;                    // [32000]
    float* h1   = out + OUTN;             // new_hidden[0]
    float* h2   = out + OUTN + HDIM;      // new_hidden[1]
    float* c1   = out + OUTN + 2 * HDIM;  // new_cell[0]
    float* c2   = out + OUTN + 3 * HDIM;  // new_cell[1]

    // Workspace layout (all 16 B aligned): gates | logits | partial.
    // partial must NOT live in the logp output region anymore: sub_fused
    // reads partials while writing logp (would race block-vs-block).
    float* gates    = (float*)d_ws;          // [8192]
    float* logits   = gates + 4 * HDIM;      // [32000]
    float2* partial = (float2*)(logits + OUTN); // [1000], 8B-aligned offset

    // layer 0: x = concat(category, input)
    lstm_gemv<<<512, 256, 0, stream>>>(category, input, hidden,
                                       w_ih_l0, w_hh_l0, b_ih_l0, b_hh_l0,
                                       gates);
    lstm_point<<<8, 256, 0, stream>>>(gates, cell, h1, c1);
    // layer 1: x = h1 (contiguous; split into two halves for the shared kernel)
    lstm_gemv<<<512, 256, 0, stream>>>(h1, h1 + 1024, hidden + HDIM,
                                       w_ih_l1, w_hh_l1, b_ih_l1, b_hh_l1,
                                       gates);
    lstm_point<<<8, 256, 0, stream>>>(gates, cell + HDIM, h2, c2);

    logits_kernel<<<NPART, 256, 0, stream>>>(category, h2, w_out, b_out,
                                             logits, partial);
    sub_fused<<<OUTN / 256, 256, 0, stream>>>(logits, partial, logp);
}